// Round 1
// baseline (1890.262 us; speedup 1.0000x reference)
//
#include <hip/hip_runtime.h>
#include <hip/hip_bf16.h>

#define Bb 8
#define Tt 512
#define Cc 32
#define Dd 128
#define TQ 32
#define SCALE 0.08838834764831845f

typedef unsigned int u32;
typedef __hip_bfloat16 bf16;

__device__ __forceinline__ float bflo(u32 u) { return __uint_as_float(u << 16); }
__device__ __forceinline__ float bfhi(u32 u) { return __uint_as_float(u & 0xffff0000u); }

// ---------------- Kernel 1: gather + QKV + rotation ----------------
// block = 128 threads (lane = output dim d), grid = B*T
__global__ __launch_bounds__(128)
void k_qkv(const float* __restrict__ x, const int* __restrict__ xm,
           const int* __restrict__ pos, const float* __restrict__ pe,
           const int* __restrict__ imp, const int* __restrict__ idxc,
           const float* __restrict__ wq, const float* __restrict__ bq,
           const float* __restrict__ wk, const float* __restrict__ bk,
           const float* __restrict__ wv, const float* __restrict__ bv,
           bf16* __restrict__ qb, bf16* __restrict__ kb, bf16* __restrict__ vb)
{
    const int bt = blockIdx.x;           // b*T + t
    const int b  = bt >> 9;              // T = 512
    const int t  = bt & 511;
    const int d  = threadIdx.x;          // 0..127

    __shared__ float xg[Cc][Dd];         // 16 KB gathered rows

    for (int c = 0; c < Cc; ++c) {
        int base = bt * Cc + c;
        int idx  = xm[base] ? imp[bt] : idxc[base];
        xg[c][d] = x[(bt * Cc + idx) * Dd + d];
    }
    __syncthreads();

    const float* Wm[3] = {wq, wk, wv};
    const float* Bm[3] = {bq, bk, bv};
    bf16*        Ob[3] = {qb, kb, vb};

    for (int m = 0; m < 3; ++m) {
        float bias = Bm[m][d];
        float acc[Cc];
#pragma unroll
        for (int c = 0; c < Cc; ++c) acc[c] = bias;

        const float4* W4 = (const float4*)(Wm[m] + (long)d * Dd);
        for (int e4 = 0; e4 < Dd / 4; ++e4) {
            float4 w = W4[e4];
#pragma unroll
            for (int c = 0; c < Cc; ++c) {
                float4 xv = *(const float4*)&xg[c][e4 * 4];
                acc[c] = fmaf(xv.x, w.x, acc[c]);
                acc[c] = fmaf(xv.y, w.y, acc[c]);
                acc[c] = fmaf(xv.z, w.z, acc[c]);
                acc[c] = fmaf(xv.w, w.w, acc[c]);
            }
        }

        bf16* dst = Ob[m];
        if (m < 2) {
            // complex rotation: pairs (2i, 2i+1) sit on adjacent lanes
#pragma unroll
            for (int c = 0; c < Cc; ++c) {
                float val = acc[c];
                float p   = __shfl_xor(val, 1, 64);
                const float* rp = pe + ((long)pos[bt * Cc + c] * (Dd / 2) + (d >> 1)) * 2;
                float r0 = rp[0], r1 = rp[1];
                // even d=2i: re = v*r0 - p*r1 ; odd d=2i+1: im = p*r1 + v*r0
                val = (d & 1) ? fmaf(p, r1, val * r0) : fmaf(val, r0, -(p * r1));
                dst[((long)(b * Cc + c) * Tt + t) * Dd + d] = __float2bfloat16(val);
            }
        } else {
#pragma unroll
            for (int c = 0; c < Cc; ++c)
                dst[((long)(b * Cc + c) * Tt + t) * Dd + d] = __float2bfloat16(acc[c]);
        }
    }
}

// ---------------- Kernel 2: attention + fused LayerNorm ----------------
// block = 256 threads: (qi 0..31) x (part 0..7, 16 dims each)
// grid = (T/TQ, B*C)
__global__ __launch_bounds__(256)
void k_attn(const bf16* __restrict__ qb, const bf16* __restrict__ kb,
            const bf16* __restrict__ vb, const float* __restrict__ x,
            const int* __restrict__ xm, const int* __restrict__ pm,
            const float* __restrict__ lsg, const float* __restrict__ lng,
            const float* __restrict__ lnb, float* __restrict__ out)
{
    const int head = blockIdx.y;          // b*C + c
    const int b    = head >> 5;           // C = 32
    const int c    = head & 31;
    const int qt0  = blockIdx.x * TQ;
    const int tid  = threadIdx.x;
    const int qi   = tid >> 3;            // 0..31
    const int part = tid & 7;             // 0..7

    __shared__ float S[TQ][Tt + 4];       // 66 KB, padded rows (bank spread)
    __shared__ float wk_[Tt];             // per-k weight
    __shared__ float pk_[Tt];             // per-token p_mask
    __shared__ uint4 kvbuf[512];          // 8 KB K/V staging chunk (32 rows)
    const bf16* kv16 = (const bf16*)kvbuf;

    for (int i = tid; i < Tt; i += 256) {
        int base = (b * Tt + i) * Cc + c;
        wk_[i] = xm[base] ? (1.0f / Tt) : 1.0f;
        pk_[i] = pm[base] ? 1.0f : 0.0f;
    }

    // q slice -> registers
    float qreg[16];
    {
        const uint4* qp = (const uint4*)(qb + ((long)head * Tt + qt0 + qi) * Dd + part * 16);
        uint4 a = qp[0], b4 = qp[1];
        u32 w[8] = {a.x, a.y, a.z, a.w, b4.x, b4.y, b4.z, b4.w};
#pragma unroll
        for (int j = 0; j < 8; ++j) { qreg[2 * j] = bflo(w[j]); qreg[2 * j + 1] = bfhi(w[j]); }
    }
    __syncthreads();

    // ---- QK^T phase ----
    for (int kc = 0; kc < Tt / 32; ++kc) {
        __syncthreads();
        const uint4* src = (const uint4*)(kb + ((long)head * Tt + kc * 32) * Dd);
        kvbuf[tid]       = src[tid];
        kvbuf[tid + 256] = src[tid + 256];
        __syncthreads();
        for (int kk = 0; kk < 32; ++kk) {
            const uint4* kp = (const uint4*)(kv16 + kk * Dd + part * 16);
            uint4 a = kp[0], b4 = kp[1];
            u32 w[8] = {a.x, a.y, a.z, a.w, b4.x, b4.y, b4.z, b4.w};
            float sum = 0.f;
#pragma unroll
            for (int j = 0; j < 8; ++j)
                sum = fmaf(qreg[2 * j], bflo(w[j]), fmaf(qreg[2 * j + 1], bfhi(w[j]), sum));
            sum += __shfl_xor(sum, 1, 64);
            sum += __shfl_xor(sum, 2, 64);
            sum += __shfl_xor(sum, 4, 64);
            if (part == 0) {
                int kt = kc * 32 + kk;
                S[qi][kt] = (pk_[kt] > 0.5f) ? -1e30f : sum * SCALE;
            }
        }
    }
    __syncthreads();

    // ---- softmax (strided scan kt = 8*j + part, conflict-free) ----
    float mx = -1e30f;
    for (int j = 0; j < Tt / 8; ++j) mx = fmaxf(mx, S[qi][j * 8 + part]);
    mx = fmaxf(mx, __shfl_xor(mx, 1, 64));
    mx = fmaxf(mx, __shfl_xor(mx, 2, 64));
    mx = fmaxf(mx, __shfl_xor(mx, 4, 64));
    float l = 0.f;
    for (int j = 0; j < Tt / 8; ++j) {
        float s = S[qi][j * 8 + part];
        float e = (s <= -1e29f) ? 0.f : __expf(s - mx);
        S[qi][j * 8 + part] = e;
        l += e;
    }
    l += __shfl_xor(l, 1, 64);
    l += __shfl_xor(l, 2, 64);
    l += __shfl_xor(l, 4, 64);
    const int t = qt0 + qi;
    // q-side mask (row fully masked -> NaN -> nan_to_num -> 0) and 1/l
    float rl = (l > 0.f && pk_[t] < 0.5f) ? 1.0f / l : 0.f;

    // ---- PV phase ----
    float acc[16];
#pragma unroll
    for (int j = 0; j < 16; ++j) acc[j] = 0.f;
    for (int kc = 0; kc < Tt / 32; ++kc) {
        __syncthreads();
        const uint4* src = (const uint4*)(vb + ((long)head * Tt + kc * 32) * Dd);
        kvbuf[tid]       = src[tid];
        kvbuf[tid + 256] = src[tid + 256];
        __syncthreads();
        for (int kk = 0; kk < 32; ++kk) {
            int kt  = kc * 32 + kk;
            float p = S[qi][kt] * wk_[kt];
            const uint4* vp = (const uint4*)(kv16 + kk * Dd + part * 16);
            uint4 a = vp[0], b4 = vp[1];
            u32 w[8] = {a.x, a.y, a.z, a.w, b4.x, b4.y, b4.z, b4.w};
#pragma unroll
            for (int j = 0; j < 8; ++j) {
                acc[2 * j]     = fmaf(p, bflo(w[j]), acc[2 * j]);
                acc[2 * j + 1] = fmaf(p, bfhi(w[j]), acc[2 * j + 1]);
            }
        }
    }

    // ---- epilogue: y = x + ls*out, LayerNorm over 8 lanes ----
    long xoff = (((long)b * Tt + t) * Cc + c) * Dd + part * 16;
    float yv[16];
    float s1 = 0.f, s2 = 0.f;
#pragma unroll
    for (int j = 0; j < 16; ++j) {
        float y = x[xoff + j] + lsg[part * 16 + j] * (acc[j] * rl);
        yv[j] = y;
        s1 += y;
        s2 += y * y;
    }
    s1 += __shfl_xor(s1, 1, 64); s1 += __shfl_xor(s1, 2, 64); s1 += __shfl_xor(s1, 4, 64);
    s2 += __shfl_xor(s2, 1, 64); s2 += __shfl_xor(s2, 2, 64); s2 += __shfl_xor(s2, 4, 64);
    float mean = s1 * (1.0f / Dd);
    float var  = s2 * (1.0f / Dd) - mean * mean;
    float rstd = rsqrtf(var + 1e-5f);
#pragma unroll
    for (int j = 0; j < 16; ++j)
        out[xoff + j] = (yv[j] - mean) * rstd * lng[part * 16 + j] + lnb[part * 16 + j];
}

extern "C" void kernel_launch(void* const* d_in, const int* in_sizes, int n_in,
                              void* d_out, int out_size, void* d_ws, size_t ws_size,
                              hipStream_t stream) {
    const float* x    = (const float*)d_in[0];
    const int* xmask  = (const int*)d_in[1];
    const int* pmask  = (const int*)d_in[2];
    const int* pos    = (const int*)d_in[3];
    const float* pe   = (const float*)d_in[4];
    const int* imp    = (const int*)d_in[5];
    const int* idxc   = (const int*)d_in[6];
    const float* wq_w = (const float*)d_in[7];
    const float* wq_b = (const float*)d_in[8];
    const float* wk_w = (const float*)d_in[9];
    const float* wk_b = (const float*)d_in[10];
    const float* wv_w = (const float*)d_in[11];
    const float* wv_b = (const float*)d_in[12];
    const float* lsg  = (const float*)d_in[13];
    const float* lng  = (const float*)d_in[14];
    const float* lnb  = (const float*)d_in[15];
    float* out = (float*)d_out;

    size_t n = (size_t)Bb * Cc * Tt * Dd;
    bf16* qb = (bf16*)d_ws;
    bf16* kb = qb + n;
    bf16* vb = kb + n;

    k_qkv<<<dim3(Bb * Tt), dim3(128), 0, stream>>>(
        x, xmask, pos, pe, imp, idxc,
        wq_w, wq_b, wk_w, wk_b, wv_w, wv_b, qb, kb, vb);
    k_attn<<<dim3(Tt / TQ, Bb * Cc), dim3(256), 0, stream>>>(
        qb, kb, vb, x, xmask, pmask, lsg, lng, lnb, out);
}

// Round 2
// 612.747 us; speedup vs baseline: 3.0849x; 3.0849x over previous
//
#include <hip/hip_runtime.h>
#include <hip/hip_bf16.h>

#define Bb 8
#define Tt 512
#define Cc 32
#define Dd 128
#define SCALE 0.08838834764831845f
#define SROW 520  // S row stride in bf16 elems (512 + 8 pad, 16B-aligned)

typedef unsigned int u32;
typedef __hip_bfloat16 bf16;
typedef __attribute__((ext_vector_type(8))) short short8;
typedef __attribute__((ext_vector_type(4))) float floatx4;

__device__ __forceinline__ float bflo(u32 u) { return __uint_as_float(u << 16); }
__device__ __forceinline__ float bfhi(u32 u) { return __uint_as_float(u & 0xffff0000u); }
__device__ __forceinline__ short f2bf(float f) {
    __hip_bfloat16 h = __float2bfloat16(f);
    return *(short*)&h;
}
__device__ __forceinline__ float bf2f(short s) {
    return __uint_as_float(((u32)(unsigned short)s) << 16);
}

// ---------------- Kernel 1: gather + QKV + rotation (unchanged, correct) ----
__global__ __launch_bounds__(128)
void k_qkv(const float* __restrict__ x, const int* __restrict__ xm,
           const int* __restrict__ pos, const float* __restrict__ pe,
           const int* __restrict__ imp, const int* __restrict__ idxc,
           const float* __restrict__ wq, const float* __restrict__ bq,
           const float* __restrict__ wk, const float* __restrict__ bk,
           const float* __restrict__ wv, const float* __restrict__ bv,
           bf16* __restrict__ qb, bf16* __restrict__ kb, bf16* __restrict__ vb)
{
    const int bt = blockIdx.x;
    const int b  = bt >> 9;
    const int t  = bt & 511;
    const int d  = threadIdx.x;

    __shared__ float xg[Cc][Dd];

    for (int c = 0; c < Cc; ++c) {
        int base = bt * Cc + c;
        int idx  = xm[base] ? imp[bt] : idxc[base];
        xg[c][d] = x[(bt * Cc + idx) * Dd + d];
    }
    __syncthreads();

    const float* Wm[3] = {wq, wk, wv};
    const float* Bm[3] = {bq, bk, bv};
    bf16*        Ob[3] = {qb, kb, vb};

    for (int m = 0; m < 3; ++m) {
        float bias = Bm[m][d];
        float acc[Cc];
#pragma unroll
        for (int c = 0; c < Cc; ++c) acc[c] = bias;

        const float4* W4 = (const float4*)(Wm[m] + (long)d * Dd);
        for (int e4 = 0; e4 < Dd / 4; ++e4) {
            float4 w = W4[e4];
#pragma unroll
            for (int c = 0; c < Cc; ++c) {
                float4 xv = *(const float4*)&xg[c][e4 * 4];
                acc[c] = fmaf(xv.x, w.x, acc[c]);
                acc[c] = fmaf(xv.y, w.y, acc[c]);
                acc[c] = fmaf(xv.z, w.z, acc[c]);
                acc[c] = fmaf(xv.w, w.w, acc[c]);
            }
        }

        bf16* dst = Ob[m];
        if (m < 2) {
#pragma unroll
            for (int c = 0; c < Cc; ++c) {
                float val = acc[c];
                float p   = __shfl_xor(val, 1, 64);
                const float* rp = pe + ((long)pos[bt * Cc + c] * (Dd / 2) + (d >> 1)) * 2;
                float r0 = rp[0], r1 = rp[1];
                val = (d & 1) ? fmaf(p, r1, val * r0) : fmaf(val, r0, -(p * r1));
                dst[((long)(b * Cc + c) * Tt + t) * Dd + d] = __float2bfloat16(val);
            }
        } else {
#pragma unroll
            for (int c = 0; c < Cc; ++c)
                dst[((long)(b * Cc + c) * Tt + t) * Dd + d] = __float2bfloat16(acc[c]);
        }
    }
}

// ---------------- Kernel 1b: V transpose [head][t][d] -> [head][d][t] -------
__global__ __launch_bounds__(256)
void k_vt(const short* __restrict__ vb, short* __restrict__ vt)
{
    const int head = blockIdx.y;
    const int t0   = blockIdx.x * 64;
    const int tid  = threadIdx.x;

    __shared__ short tile[64 * 136];  // 64 t-rows x 128 d (pad 8)

    const short* src = vb + ((long)head * Tt + t0) * Dd;
#pragma unroll
    for (int i = 0; i < 4; ++i) {
        int u = tid + i * 256;              // 0..1023 uint4-granules
        int row = u >> 4, col = (u & 15) * 8;
        *(short8*)&tile[row * 136 + col] = *(const short8*)(src + row * Dd + col);
    }
    __syncthreads();

    short* dst = vt + (long)head * Dd * Tt + t0;
#pragma unroll
    for (int i = 0; i < 4; ++i) {
        int u = tid + i * 256;              // 0..1023
        int d = u >> 3, t8 = (u & 7) * 8;
        short8 v;
#pragma unroll
        for (int j = 0; j < 8; ++j) v[j] = tile[(t8 + j) * 136 + d];
        *(short8*)(dst + (long)d * Tt + t8) = v;
    }
}

// ---------------- Kernel 2: MFMA attention + fused LayerNorm ----------------
// block = 256 (4 waves), grid = (T/32, B*C). TQ=32 queries per block.
__global__ __launch_bounds__(256)
void k_attn(const short* __restrict__ qb, const short* __restrict__ kbp,
            const short* __restrict__ vtp, const float* __restrict__ x,
            const int* __restrict__ xm, const int* __restrict__ pm,
            const float* __restrict__ lsg, const float* __restrict__ lng,
            const float* __restrict__ lnb, float* __restrict__ out)
{
    const int head = blockIdx.y;
    const int b    = head >> 5;
    const int c    = head & 31;
    const int qt0  = blockIdx.x * 32;
    const int tid  = threadIdx.x;
    const int w    = tid >> 6;     // wave 0..3
    const int lane = tid & 63;
    const int quad = lane >> 4;    // 0..3
    const int m    = lane & 15;    // 0..15

    __shared__ short S[32 * SROW];       // 33.3 KB scores->P (bf16)
    __shared__ short KV[128 * 72];       // 18.4 KB K chunk (64x136) / Vt chunk (128x72)
    __shared__ float wk_[Tt];
    __shared__ float pk_[Tt];
    __shared__ float rlS[32];
    __shared__ float ps1[4][32];
    __shared__ float ps2[4][32];
    __shared__ float mrs[32][2];

    for (int i = tid; i < Tt; i += 256) {
        int base = (b * Tt + i) * Cc + c;
        wk_[i] = xm[base] ? (1.0f / Tt) : 1.0f;
        pk_[i] = pm[base] ? 1.0f : 0.0f;
    }

    // Q A-fragments in registers: qf[qtile][kb], lane holds Q[q=qt*16+m][kb*32+quad*8 .. +7]
    short8 qf[2][4];
#pragma unroll
    for (int qt = 0; qt < 2; ++qt)
#pragma unroll
        for (int kb = 0; kb < 4; ++kb)
            qf[qt][kb] = *(const short8*)(qb + ((long)head * Tt + qt0 + qt * 16 + m) * Dd
                                          + kb * 32 + quad * 8);

    // ---- QK^T phase: S[q][kt] = mask ? -inf : score*SCALE (bf16) ----
    for (int ch = 0; ch < 8; ++ch) {
        __syncthreads();
        const short* src = kbp + ((long)head * Tt + ch * 64) * Dd;
#pragma unroll
        for (int i = 0; i < 4; ++i) {
            int u = tid + i * 256;
            int row = u >> 4, col = (u & 15) * 8;
            *(short8*)&KV[row * 136 + col] = *(const short8*)(src + row * Dd + col);
        }
        __syncthreads();

        floatx4 sc0 = {0.f, 0.f, 0.f, 0.f}, sc1 = {0.f, 0.f, 0.f, 0.f};
#pragma unroll
        for (int kb = 0; kb < 4; ++kb) {
            short8 bk = *(const short8*)&KV[(w * 16 + m) * 136 + kb * 32 + quad * 8];
            sc0 = __builtin_amdgcn_mfma_f32_16x16x32_bf16(qf[0][kb], bk, sc0, 0, 0, 0);
            sc1 = __builtin_amdgcn_mfma_f32_16x16x32_bf16(qf[1][kb], bk, sc1, 0, 0, 0);
        }
        int kt = ch * 64 + w * 16 + m;
        bool masked = pk_[kt] > 0.5f;
#pragma unroll
        for (int r = 0; r < 4; ++r) {
            float v0 = masked ? -1e30f : sc0[r] * SCALE;
            float v1 = masked ? -1e30f : sc1[r] * SCALE;
            S[(quad * 4 + r) * SROW + kt]      = f2bf(v0);
            S[(16 + quad * 4 + r) * SROW + kt] = f2bf(v1);
        }
    }
    __syncthreads();

    // ---- softmax: P = exp(s-mx)*wk (bf16), rl = 1/l (or 0) ----
    {
        int qi = tid >> 3, part = tid & 7;
        float mx = -1e30f;
        for (int j = 0; j < 64; ++j) mx = fmaxf(mx, bf2f(S[qi * SROW + j * 8 + part]));
        mx = fmaxf(mx, __shfl_xor(mx, 1, 64));
        mx = fmaxf(mx, __shfl_xor(mx, 2, 64));
        mx = fmaxf(mx, __shfl_xor(mx, 4, 64));
        float l = 0.f;
        for (int j = 0; j < 64; ++j) {
            int kt = j * 8 + part;
            float s = bf2f(S[qi * SROW + kt]);
            float e = (s <= -1e29f) ? 0.f : __expf(s - mx);
            S[qi * SROW + kt] = f2bf(e * wk_[kt]);
            l += e;
        }
        l += __shfl_xor(l, 1, 64);
        l += __shfl_xor(l, 2, 64);
        l += __shfl_xor(l, 4, 64);
        if (part == 0)
            rlS[qi] = (l > 0.f && pk_[qt0 + qi] < 0.5f) ? 1.0f / l : 0.f;
    }
    __syncthreads();

    // ---- PV phase: O[q][d] = sum_kt P[q][kt] * V[kt][d] ----
    floatx4 oa[2][2];
#pragma unroll
    for (int qt = 0; qt < 2; ++qt)
#pragma unroll
        for (int dt = 0; dt < 2; ++dt) oa[qt][dt] = (floatx4){0.f, 0.f, 0.f, 0.f};

    for (int ch = 0; ch < 8; ++ch) {
        __syncthreads();
        const short* vsrc = vtp + (long)head * Dd * Tt + ch * 64;
#pragma unroll
        for (int i = 0; i < 4; ++i) {
            int u = tid + i * 256;
            int d = u >> 3, t8 = (u & 7) * 8;
            *(short8*)&KV[d * 72 + t8] = *(const short8*)(vsrc + (long)d * Tt + t8);
        }
        __syncthreads();

#pragma unroll
        for (int kb = 0; kb < 2; ++kb) {
            short8 bv0 = *(const short8*)&KV[((w * 2 + 0) * 16 + m) * 72 + kb * 32 + quad * 8];
            short8 bv1 = *(const short8*)&KV[((w * 2 + 1) * 16 + m) * 72 + kb * 32 + quad * 8];
#pragma unroll
            for (int qt = 0; qt < 2; ++qt) {
                short8 ap = *(const short8*)&S[(qt * 16 + m) * SROW + ch * 64 + kb * 32 + quad * 8];
                oa[qt][0] = __builtin_amdgcn_mfma_f32_16x16x32_bf16(ap, bv0, oa[qt][0], 0, 0, 0);
                oa[qt][1] = __builtin_amdgcn_mfma_f32_16x16x32_bf16(ap, bv1, oa[qt][1], 0, 0, 0);
            }
        }
    }

    // ---- epilogue: y = x + ls*(O*rl); LayerNorm over d=128 (cross-wave) ----
    float yv[2][2][4];
    float s1[2][4], s2[2][4];
#pragma unroll
    for (int qt = 0; qt < 2; ++qt)
#pragma unroll
        for (int r = 0; r < 4; ++r) { s1[qt][r] = 0.f; s2[qt][r] = 0.f; }

#pragma unroll
    for (int qt = 0; qt < 2; ++qt)
#pragma unroll
        for (int dt = 0; dt < 2; ++dt) {
            int d = (w * 2 + dt) * 16 + m;
            float lg = lsg[d];
#pragma unroll
            for (int r = 0; r < 4; ++r) {
                int row = qt * 16 + quad * 4 + r;
                int t = qt0 + row;
                float val = oa[qt][dt][r] * rlS[row];
                float y = x[(((long)b * Tt + t) * Cc + c) * Dd + d] + lg * val;
                yv[qt][dt][r] = y;
                s1[qt][r] += y;
                s2[qt][r] += y * y;
            }
        }
#pragma unroll
    for (int qt = 0; qt < 2; ++qt)
#pragma unroll
        for (int r = 0; r < 4; ++r) {
            float a = s1[qt][r], bb = s2[qt][r];
            a += __shfl_xor(a, 1, 64); bb += __shfl_xor(bb, 1, 64);
            a += __shfl_xor(a, 2, 64); bb += __shfl_xor(bb, 2, 64);
            a += __shfl_xor(a, 4, 64); bb += __shfl_xor(bb, 4, 64);
            a += __shfl_xor(a, 8, 64); bb += __shfl_xor(bb, 8, 64);
            if (m == 0) {
                ps1[w][qt * 16 + quad * 4 + r] = a;
                ps2[w][qt * 16 + quad * 4 + r] = bb;
            }
        }
    __syncthreads();
    if (tid < 32) {
        float a = 0.f, bb = 0.f;
#pragma unroll
        for (int wv = 0; wv < 4; ++wv) { a += ps1[wv][tid]; bb += ps2[wv][tid]; }
        float mean = a * (1.0f / Dd);
        float var  = bb * (1.0f / Dd) - mean * mean;
        mrs[tid][0] = mean;
        mrs[tid][1] = rsqrtf(var + 1e-5f);
    }
    __syncthreads();

#pragma unroll
    for (int qt = 0; qt < 2; ++qt)
#pragma unroll
        for (int dt = 0; dt < 2; ++dt) {
            int d = (w * 2 + dt) * 16 + m;
            float g = lng[d], be = lnb[d];
#pragma unroll
            for (int r = 0; r < 4; ++r) {
                int row = qt * 16 + quad * 4 + r;
                int t = qt0 + row;
                out[(((long)b * Tt + t) * Cc + c) * Dd + d] =
                    (yv[qt][dt][r] - mrs[row][0]) * mrs[row][1] * g + be;
            }
        }
}

extern "C" void kernel_launch(void* const* d_in, const int* in_sizes, int n_in,
                              void* d_out, int out_size, void* d_ws, size_t ws_size,
                              hipStream_t stream) {
    const float* x    = (const float*)d_in[0];
    const int* xmask  = (const int*)d_in[1];
    const int* pmask  = (const int*)d_in[2];
    const int* pos    = (const int*)d_in[3];
    const float* pe   = (const float*)d_in[4];
    const int* imp    = (const int*)d_in[5];
    const int* idxc   = (const int*)d_in[6];
    const float* wq_w = (const float*)d_in[7];
    const float* wq_b = (const float*)d_in[8];
    const float* wk_w = (const float*)d_in[9];
    const float* wk_b = (const float*)d_in[10];
    const float* wv_w = (const float*)d_in[11];
    const float* wv_b = (const float*)d_in[12];
    const float* lsg  = (const float*)d_in[13];
    const float* lng  = (const float*)d_in[14];
    const float* lnb  = (const float*)d_in[15];
    float* out = (float*)d_out;

    size_t n = (size_t)Bb * Cc * Tt * Dd;
    bf16* qb = (bf16*)d_ws;
    bf16* kb = qb + n;
    bf16* vb = kb + n;
    bf16* vt = vb + n;

    k_qkv<<<dim3(Bb * Tt), dim3(128), 0, stream>>>(
        x, xmask, pos, pe, imp, idxc,
        wq_w, wq_b, wk_w, wk_b, wv_w, wv_b, qb, kb, vb);
    k_vt<<<dim3(Tt / 64, Bb * Cc), dim3(256), 0, stream>>>(
        (const short*)vb, (short*)vt);
    k_attn<<<dim3(Tt / 32, Bb * Cc), dim3(256), 0, stream>>>(
        (const short*)qb, (const short*)kb, (const short*)vt, x,
        xmask, pmask, lsg, lng, lnb, out);
}

// Round 3
// 369.647 us; speedup vs baseline: 5.1137x; 1.6577x over previous
//
#include <hip/hip_runtime.h>
#include <hip/hip_bf16.h>

#define Bb 8
#define Tt 512
#define Cc 32
#define Dd 128
#define SCALE 0.08838834764831845f
#define SROW 520  // S row stride in bf16 elems (512 + 8 pad, 16B-aligned)

typedef unsigned int u32;
typedef __hip_bfloat16 bf16;
typedef __attribute__((ext_vector_type(8))) short short8;
typedef __attribute__((ext_vector_type(4))) short short4v;
typedef __attribute__((ext_vector_type(4))) float floatx4;

__device__ __forceinline__ short f2bf(float f) {
    __hip_bfloat16 h = __float2bfloat16(f);
    return *(short*)&h;
}
__device__ __forceinline__ float bf2f(short s) {
    return __uint_as_float(((u32)(unsigned short)s) << 16);
}

// ---------------- Kernel 0: W f32 -> bf16 ----------------
__global__ __launch_bounds__(256)
void k_wconv(const float* __restrict__ wq, const float* __restrict__ wk,
             const float* __restrict__ wv, short* __restrict__ Wb)
{
    int g = blockIdx.x * 256 + threadIdx.x;     // 0 .. 3*16384-1
    int mat = g >> 14, rem = g & 16383;
    const float* src = (mat == 0) ? wq : (mat == 1) ? wk : wv;
    Wb[g] = f2bf(src[rem]);
}

// ---------------- Kernel 1: gather + QKV (MFMA) + rotation ----------------
// block = 256 (4 waves); 64 rows (2 t x 32 c) x 384 cols; grid = B*T*C/64
__global__ __launch_bounds__(256)
void k_qkvm(const float* __restrict__ x, const int* __restrict__ xm,
            const int* __restrict__ pos, const float* __restrict__ pe,
            const int* __restrict__ imp, const int* __restrict__ idxc,
            const short* __restrict__ Wb,
            const float* __restrict__ bq, const float* __restrict__ bk,
            const float* __restrict__ bv,
            short* __restrict__ qb, short* __restrict__ kb, short* __restrict__ vb)
{
    const int R0  = blockIdx.x * 64;     // rows R = (b*512 + t)*32 + c
    const int b   = R0 >> 14;
    const int t0  = (R0 >> 5) & 511;
    const int tid = threadIdx.x;
    const int w    = tid >> 6;
    const int lane = tid & 63;
    const int quad = lane >> 4;
    const int m    = lane & 15;

    __shared__ short xg[64 * 136];   // gathered rows, bf16
    __shared__ short ot[64 * 392];   // output tile: [row][mat*128 + d]

    // ---- gather + convert to bf16 ----
#pragma unroll
    for (int i = 0; i < 8; ++i) {
        int u   = tid + i * 256;     // 2048 float4-granules
        int row = u >> 5, seg = u & 31;
        int R   = R0 + row;
        int idx = xm[R] ? imp[R >> 5] : idxc[R];
        float4 v = *(const float4*)(x + ((long)(R >> 5) * Cc + idx) * Dd + seg * 4);
        short4v s = {f2bf(v.x), f2bf(v.y), f2bf(v.z), f2bf(v.w)};
        *(short4v*)&xg[row * 136 + seg * 4] = s;
    }

    // ---- W fragments (registers, reused across row-tiles) ----
    // slot sl = mat*2 + h; col-tile within matrix ct = h*4 + w; col d = ct*16 + m
    short8 wf[6][4];
    float  bias_v[6];
#pragma unroll
    for (int mat = 0; mat < 3; ++mat) {
        const float* bp = (mat == 0) ? bq : (mat == 1) ? bk : bv;
#pragma unroll
        for (int h = 0; h < 2; ++h) {
            int sl = mat * 2 + h;
            int ct = h * 4 + w;
            bias_v[sl] = bp[ct * 16 + m];
#pragma unroll
            for (int kb = 0; kb < 4; ++kb)
                wf[sl][kb] = *(const short8*)(Wb + ((long)mat * 128 + ct * 16 + m) * 128
                                              + kb * 32 + quad * 8);
        }
    }
    __syncthreads();

    // ---- 4 row-tiles of 16 ----
    for (int rt = 0; rt < 4; ++rt) {
        short8 af[4];
#pragma unroll
        for (int kb = 0; kb < 4; ++kb)
            af[kb] = *(const short8*)&xg[(rt * 16 + m) * 136 + kb * 32 + quad * 8];

        floatx4 acc[6];
#pragma unroll
        for (int sl = 0; sl < 6; ++sl) acc[sl] = (floatx4){0.f, 0.f, 0.f, 0.f};
#pragma unroll
        for (int kb = 0; kb < 4; ++kb)
#pragma unroll
            for (int sl = 0; sl < 6; ++sl)
                acc[sl] = __builtin_amdgcn_mfma_f32_16x16x32_bf16(af[kb], wf[sl][kb], acc[sl], 0, 0, 0);

        // pos per output row (shared by all slots)
        int po[4];
#pragma unroll
        for (int r = 0; r < 4; ++r) po[r] = pos[R0 + rt * 16 + quad * 4 + r];

        // epilogue: +bias, rotate q/k, stash bf16 in LDS out-tile
#pragma unroll
        for (int sl = 0; sl < 6; ++sl) {
            int mat = sl >> 1;
            int ct  = (sl & 1) * 4 + w;
            int d   = ct * 16 + m;
#pragma unroll
            for (int r = 0; r < 4; ++r) {
                float v = acc[sl][r] + bias_v[sl];
                float p = __shfl_xor(v, 1, 64);
                if (mat < 2) {
                    const float* rp = pe + ((long)po[r] * (Dd / 2) + (d >> 1)) * 2;
                    float r0 = rp[0], r1 = rp[1];
                    v = (d & 1) ? fmaf(p, r1, v * r0) : fmaf(v, r0, -(p * r1));
                }
                ot[(rt * 16 + quad * 4 + r) * 392 + mat * 128 + d] = f2bf(v);
            }
        }
    }
    __syncthreads();

    // ---- coalesced writes: per mat, 64 rows x 256B ----
    short* const mats[3] = {qb, kb, vb};
#pragma unroll
    for (int mat = 0; mat < 3; ++mat) {
        short* dst = mats[mat];
#pragma unroll
        for (int i = 0; i < 4; ++i) {
            int g = tid + i * 256;          // 1024 granules of 16B
            int n = g >> 4, off = (g & 15) * 8;
            int c = n & 31, tl = n >> 5;
            *(short8*)(dst + (((long)(b * Cc + c) * Tt) + t0 + tl) * Dd + off) =
                *(const short8*)&ot[n * 392 + mat * 128 + off];
        }
    }
}

// ---------------- Kernel 1b: V transpose [head][t][d] -> [head][d][t] -------
__global__ __launch_bounds__(256)
void k_vt(const short* __restrict__ vb, short* __restrict__ vt)
{
    const int head = blockIdx.y;
    const int t0   = blockIdx.x * 64;
    const int tid  = threadIdx.x;

    __shared__ short tile[64 * 136];

    const short* src = vb + ((long)head * Tt + t0) * Dd;
#pragma unroll
    for (int i = 0; i < 4; ++i) {
        int u = tid + i * 256;
        int row = u >> 4, col = (u & 15) * 8;
        *(short8*)&tile[row * 136 + col] = *(const short8*)(src + row * Dd + col);
    }
    __syncthreads();

    short* dst = vt + (long)head * Dd * Tt + t0;
#pragma unroll
    for (int i = 0; i < 4; ++i) {
        int u = tid + i * 256;
        int d = u >> 3, t8 = (u & 7) * 8;
        short8 v;
#pragma unroll
        for (int j = 0; j < 8; ++j) v[j] = tile[(t8 + j) * 136 + d];
        *(short8*)(dst + (long)d * Tt + t8) = v;
    }
}

// ---------------- Kernel 2: MFMA attention + fused LayerNorm ----------------
__global__ __launch_bounds__(256)
void k_attn(const short* __restrict__ qb, const short* __restrict__ kbp,
            const short* __restrict__ vtp, const float* __restrict__ x,
            const int* __restrict__ xm, const int* __restrict__ pm,
            const float* __restrict__ lsg, const float* __restrict__ lng,
            const float* __restrict__ lnb, float* __restrict__ out)
{
    const int head = blockIdx.y;
    const int b    = head >> 5;
    const int c    = head & 31;
    const int qt0  = blockIdx.x * 32;
    const int tid  = threadIdx.x;
    const int w    = tid >> 6;
    const int lane = tid & 63;
    const int quad = lane >> 4;
    const int m    = lane & 15;

    __shared__ short S[32 * SROW];
    __shared__ short KV[128 * 72];
    __shared__ float wk_[Tt];
    __shared__ float pk_[Tt];
    __shared__ float rlS[32];
    __shared__ float ps1[4][32];
    __shared__ float ps2[4][32];
    __shared__ float mrs[32][2];

    for (int i = tid; i < Tt; i += 256) {
        int base = (b * Tt + i) * Cc + c;
        wk_[i] = xm[base] ? (1.0f / Tt) : 1.0f;
        pk_[i] = pm[base] ? 1.0f : 0.0f;
    }

    short8 qf[2][4];
#pragma unroll
    for (int qt = 0; qt < 2; ++qt)
#pragma unroll
        for (int kb = 0; kb < 4; ++kb)
            qf[qt][kb] = *(const short8*)(qb + ((long)head * Tt + qt0 + qt * 16 + m) * Dd
                                          + kb * 32 + quad * 8);

    for (int ch = 0; ch < 8; ++ch) {
        __syncthreads();
        const short* src = kbp + ((long)head * Tt + ch * 64) * Dd;
#pragma unroll
        for (int i = 0; i < 4; ++i) {
            int u = tid + i * 256;
            int row = u >> 4, col = (u & 15) * 8;
            *(short8*)&KV[row * 136 + col] = *(const short8*)(src + row * Dd + col);
        }
        __syncthreads();

        floatx4 sc0 = {0.f, 0.f, 0.f, 0.f}, sc1 = {0.f, 0.f, 0.f, 0.f};
#pragma unroll
        for (int kb = 0; kb < 4; ++kb) {
            short8 bk = *(const short8*)&KV[(w * 16 + m) * 136 + kb * 32 + quad * 8];
            sc0 = __builtin_amdgcn_mfma_f32_16x16x32_bf16(qf[0][kb], bk, sc0, 0, 0, 0);
            sc1 = __builtin_amdgcn_mfma_f32_16x16x32_bf16(qf[1][kb], bk, sc1, 0, 0, 0);
        }
        int kt = ch * 64 + w * 16 + m;
        bool masked = pk_[kt] > 0.5f;
#pragma unroll
        for (int r = 0; r < 4; ++r) {
            float v0 = masked ? -1e30f : sc0[r] * SCALE;
            float v1 = masked ? -1e30f : sc1[r] * SCALE;
            S[(quad * 4 + r) * SROW + kt]      = f2bf(v0);
            S[(16 + quad * 4 + r) * SROW + kt] = f2bf(v1);
        }
    }
    __syncthreads();

    {
        int qi = tid >> 3, part = tid & 7;
        float mx = -1e30f;
        for (int j = 0; j < 64; ++j) mx = fmaxf(mx, bf2f(S[qi * SROW + j * 8 + part]));
        mx = fmaxf(mx, __shfl_xor(mx, 1, 64));
        mx = fmaxf(mx, __shfl_xor(mx, 2, 64));
        mx = fmaxf(mx, __shfl_xor(mx, 4, 64));
        float l = 0.f;
        for (int j = 0; j < 64; ++j) {
            int kt = j * 8 + part;
            float s = bf2f(S[qi * SROW + kt]);
            float e = (s <= -1e29f) ? 0.f : __expf(s - mx);
            S[qi * SROW + kt] = f2bf(e * wk_[kt]);
            l += e;
        }
        l += __shfl_xor(l, 1, 64);
        l += __shfl_xor(l, 2, 64);
        l += __shfl_xor(l, 4, 64);
        if (part == 0)
            rlS[qi] = (l > 0.f && pk_[qt0 + qi] < 0.5f) ? 1.0f / l : 0.f;
    }
    __syncthreads();

    floatx4 oa[2][2];
#pragma unroll
    for (int qt = 0; qt < 2; ++qt)
#pragma unroll
        for (int dt = 0; dt < 2; ++dt) oa[qt][dt] = (floatx4){0.f, 0.f, 0.f, 0.f};

    for (int ch = 0; ch < 8; ++ch) {
        __syncthreads();
        const short* vsrc = vtp + (long)head * Dd * Tt + ch * 64;
#pragma unroll
        for (int i = 0; i < 4; ++i) {
            int u = tid + i * 256;
            int d = u >> 3, t8 = (u & 7) * 8;
            *(short8*)&KV[d * 72 + t8] = *(const short8*)(vsrc + (long)d * Tt + t8);
        }
        __syncthreads();

#pragma unroll
        for (int kb = 0; kb < 2; ++kb) {
            short8 bv0 = *(const short8*)&KV[((w * 2 + 0) * 16 + m) * 72 + kb * 32 + quad * 8];
            short8 bv1 = *(const short8*)&KV[((w * 2 + 1) * 16 + m) * 72 + kb * 32 + quad * 8];
#pragma unroll
            for (int qt = 0; qt < 2; ++qt) {
                short8 ap = *(const short8*)&S[(qt * 16 + m) * SROW + ch * 64 + kb * 32 + quad * 8];
                oa[qt][0] = __builtin_amdgcn_mfma_f32_16x16x32_bf16(ap, bv0, oa[qt][0], 0, 0, 0);
                oa[qt][1] = __builtin_amdgcn_mfma_f32_16x16x32_bf16(ap, bv1, oa[qt][1], 0, 0, 0);
            }
        }
    }

    float yv[2][2][4];
    float s1[2][4], s2[2][4];
#pragma unroll
    for (int qt = 0; qt < 2; ++qt)
#pragma unroll
        for (int r = 0; r < 4; ++r) { s1[qt][r] = 0.f; s2[qt][r] = 0.f; }

#pragma unroll
    for (int qt = 0; qt < 2; ++qt)
#pragma unroll
        for (int dt = 0; dt < 2; ++dt) {
            int d = (w * 2 + dt) * 16 + m;
            float lg = lsg[d];
#pragma unroll
            for (int r = 0; r < 4; ++r) {
                int row = qt * 16 + quad * 4 + r;
                int t = qt0 + row;
                float val = oa[qt][dt][r] * rlS[row];
                float y = x[(((long)b * Tt + t) * Cc + c) * Dd + d] + lg * val;
                yv[qt][dt][r] = y;
                s1[qt][r] += y;
                s2[qt][r] += y * y;
            }
        }
#pragma unroll
    for (int qt = 0; qt < 2; ++qt)
#pragma unroll
        for (int r = 0; r < 4; ++r) {
            float a = s1[qt][r], bb = s2[qt][r];
            a += __shfl_xor(a, 1, 64); bb += __shfl_xor(bb, 1, 64);
            a += __shfl_xor(a, 2, 64); bb += __shfl_xor(bb, 2, 64);
            a += __shfl_xor(a, 4, 64); bb += __shfl_xor(bb, 4, 64);
            a += __shfl_xor(a, 8, 64); bb += __shfl_xor(bb, 8, 64);
            if (m == 0) {
                ps1[w][qt * 16 + quad * 4 + r] = a;
                ps2[w][qt * 16 + quad * 4 + r] = bb;
            }
        }
    __syncthreads();
    if (tid < 32) {
        float a = 0.f, bb = 0.f;
#pragma unroll
        for (int wv = 0; wv < 4; ++wv) { a += ps1[wv][tid]; bb += ps2[wv][tid]; }
        float mean = a * (1.0f / Dd);
        float var  = bb * (1.0f / Dd) - mean * mean;
        mrs[tid][0] = mean;
        mrs[tid][1] = rsqrtf(var + 1e-5f);
    }
    __syncthreads();

#pragma unroll
    for (int qt = 0; qt < 2; ++qt)
#pragma unroll
        for (int dt = 0; dt < 2; ++dt) {
            int d = (w * 2 + dt) * 16 + m;
            float g = lng[d], be = lnb[d];
#pragma unroll
            for (int r = 0; r < 4; ++r) {
                int row = qt * 16 + quad * 4 + r;
                int t = qt0 + row;
                out[(((long)b * Tt + t) * Cc + c) * Dd + d] =
                    (yv[qt][dt][r] - mrs[row][0]) * mrs[row][1] * g + be;
            }
        }
}

extern "C" void kernel_launch(void* const* d_in, const int* in_sizes, int n_in,
                              void* d_out, int out_size, void* d_ws, size_t ws_size,
                              hipStream_t stream) {
    const float* x    = (const float*)d_in[0];
    const int* xmask  = (const int*)d_in[1];
    const int* pmask  = (const int*)d_in[2];
    const int* pos    = (const int*)d_in[3];
    const float* pe   = (const float*)d_in[4];
    const int* imp    = (const int*)d_in[5];
    const int* idxc   = (const int*)d_in[6];
    const float* wq_w = (const float*)d_in[7];
    const float* wq_b = (const float*)d_in[8];
    const float* wk_w = (const float*)d_in[9];
    const float* wk_b = (const float*)d_in[10];
    const float* wv_w = (const float*)d_in[11];
    const float* wv_b = (const float*)d_in[12];
    const float* lsg  = (const float*)d_in[13];
    const float* lng  = (const float*)d_in[14];
    const float* lnb  = (const float*)d_in[15];
    float* out = (float*)d_out;

    size_t n = (size_t)Bb * Cc * Tt * Dd;
    short* qb = (short*)d_ws;
    short* kb = qb + n;
    short* vb = kb + n;
    short* vt = vb + n;
    short* Wb = vt + n;

    k_wconv<<<dim3(3 * Dd * Dd / 256), dim3(256), 0, stream>>>(wq_w, wk_w, wv_w, Wb);
    k_qkvm<<<dim3(Bb * Tt * Cc / 64), dim3(256), 0, stream>>>(
        x, xmask, pos, pe, imp, idxc, Wb, wq_b, wk_b, wv_b, qb, kb, vb);
    k_vt<<<dim3(Tt / 64, Bb * Cc), dim3(256), 0, stream>>>(vb, vt);
    k_attn<<<dim3(Tt / 32, Bb * Cc), dim3(256), 0, stream>>>(
        qb, kb, vt, x, xmask, pmask, lsg, lng, lnb, out);
}

// Round 4
// 351.849 us; speedup vs baseline: 5.3724x; 1.0506x over previous
//
#include <hip/hip_runtime.h>
#include <hip/hip_bf16.h>

#define Bb 8
#define Tt 512
#define Cc 32
#define Dd 128
#define SCALE 0.08838834764831845f
#define SROW 520  // S row stride in bf16 elems (512 + 8 pad, 16B-aligned)

typedef unsigned int u32;
typedef __hip_bfloat16 bf16;
typedef __attribute__((ext_vector_type(8))) short short8;
typedef __attribute__((ext_vector_type(4))) short short4v;
typedef __attribute__((ext_vector_type(4))) float floatx4;

__device__ __forceinline__ short f2bf(float f) {
    __hip_bfloat16 h = __float2bfloat16(f);
    return *(short*)&h;
}
__device__ __forceinline__ float bf2f(short s) {
    return __uint_as_float(((u32)(unsigned short)s) << 16);
}

// ---------------- Kernel 0: W f32 -> bf16 ----------------
__global__ __launch_bounds__(256)
void k_wconv(const float* __restrict__ wq, const float* __restrict__ wk,
             const float* __restrict__ wv, short* __restrict__ Wb)
{
    int g = blockIdx.x * 256 + threadIdx.x;
    int mat = g >> 14, rem = g & 16383;
    const float* src = (mat == 0) ? wq : (mat == 1) ? wk : wv;
    Wb[g] = f2bf(src[rem]);
}

// ---------------- Kernel 1: gather + QKV (MFMA) + rotation + q*SCALE -------
__global__ __launch_bounds__(256)
void k_qkvm(const float* __restrict__ x, const int* __restrict__ xm,
            const int* __restrict__ pos, const float* __restrict__ pe,
            const int* __restrict__ imp, const int* __restrict__ idxc,
            const short* __restrict__ Wb,
            const float* __restrict__ bq, const float* __restrict__ bk,
            const float* __restrict__ bv,
            short* __restrict__ qb, short* __restrict__ kb, short* __restrict__ vb)
{
    const int R0  = blockIdx.x * 64;
    const int b   = R0 >> 14;
    const int t0  = (R0 >> 5) & 511;
    const int tid = threadIdx.x;
    const int w    = tid >> 6;
    const int lane = tid & 63;
    const int quad = lane >> 4;
    const int m    = lane & 15;

    __shared__ short xg[64 * 136];
    __shared__ short ot[64 * 392];

#pragma unroll
    for (int i = 0; i < 8; ++i) {
        int u   = tid + i * 256;
        int row = u >> 5, seg = u & 31;
        int R   = R0 + row;
        int idx = xm[R] ? imp[R >> 5] : idxc[R];
        float4 v = *(const float4*)(x + ((long)(R >> 5) * Cc + idx) * Dd + seg * 4);
        short4v s = {f2bf(v.x), f2bf(v.y), f2bf(v.z), f2bf(v.w)};
        *(short4v*)&xg[row * 136 + seg * 4] = s;
    }

    short8 wf[6][4];
    float  bias_v[6];
#pragma unroll
    for (int mat = 0; mat < 3; ++mat) {
        const float* bp = (mat == 0) ? bq : (mat == 1) ? bk : bv;
#pragma unroll
        for (int h = 0; h < 2; ++h) {
            int sl = mat * 2 + h;
            int ct = h * 4 + w;
            bias_v[sl] = bp[ct * 16 + m];
#pragma unroll
            for (int kb = 0; kb < 4; ++kb)
                wf[sl][kb] = *(const short8*)(Wb + ((long)mat * 128 + ct * 16 + m) * 128
                                              + kb * 32 + quad * 8);
        }
    }
    __syncthreads();

    for (int rt = 0; rt < 4; ++rt) {
        short8 af[4];
#pragma unroll
        for (int kb = 0; kb < 4; ++kb)
            af[kb] = *(const short8*)&xg[(rt * 16 + m) * 136 + kb * 32 + quad * 8];

        floatx4 acc[6];
#pragma unroll
        for (int sl = 0; sl < 6; ++sl) acc[sl] = (floatx4){0.f, 0.f, 0.f, 0.f};
#pragma unroll
        for (int kb = 0; kb < 4; ++kb)
#pragma unroll
            for (int sl = 0; sl < 6; ++sl)
                acc[sl] = __builtin_amdgcn_mfma_f32_16x16x32_bf16(af[kb], wf[sl][kb], acc[sl], 0, 0, 0);

        int po[4];
#pragma unroll
        for (int r = 0; r < 4; ++r) po[r] = pos[R0 + rt * 16 + quad * 4 + r];

#pragma unroll
        for (int sl = 0; sl < 6; ++sl) {
            int mat = sl >> 1;
            int ct  = (sl & 1) * 4 + w;
            int d   = ct * 16 + m;
#pragma unroll
            for (int r = 0; r < 4; ++r) {
                float v = acc[sl][r] + bias_v[sl];
                float p = __shfl_xor(v, 1, 64);
                if (mat < 2) {
                    const float* rp = pe + ((long)po[r] * (Dd / 2) + (d >> 1)) * 2;
                    float r0 = rp[0], r1 = rp[1];
                    v = (d & 1) ? fmaf(p, r1, v * r0) : fmaf(v, r0, -(p * r1));
                    if (mat == 0) v *= SCALE;   // fold 1/sqrt(D) into q
                }
                ot[(rt * 16 + quad * 4 + r) * 392 + mat * 128 + d] = f2bf(v);
            }
        }
    }
    __syncthreads();

    short* const mats[3] = {qb, kb, vb};
#pragma unroll
    for (int mat = 0; mat < 3; ++mat) {
        short* dst = mats[mat];
#pragma unroll
        for (int i = 0; i < 4; ++i) {
            int g = tid + i * 256;
            int n = g >> 4, off = (g & 15) * 8;
            int c = n & 31, tl = n >> 5;
            *(short8*)(dst + (((long)(b * Cc + c) * Tt) + t0 + tl) * Dd + off) =
                *(const short8*)&ot[n * 392 + mat * 128 + off];
        }
    }
}

// ---------------- Kernel 1b: V transpose + wk fold ----------------
__global__ __launch_bounds__(256)
void k_vt(const short* __restrict__ vb, const int* __restrict__ xm,
          short* __restrict__ vt)
{
    const int head = blockIdx.y;
    const int b    = head >> 5;
    const int c    = head & 31;
    const int t0   = blockIdx.x * 64;
    const int tid  = threadIdx.x;

    __shared__ short tile[64 * 136];
    __shared__ float wks[64];

    if (tid < 64)
        wks[tid] = xm[((long)b * Tt + t0 + tid) * Cc + c] ? (1.0f / Tt) : 1.0f;

    const short* src = vb + ((long)head * Tt + t0) * Dd;
#pragma unroll
    for (int i = 0; i < 4; ++i) {
        int u = tid + i * 256;
        int row = u >> 4, col = (u & 15) * 8;
        *(short8*)&tile[row * 136 + col] = *(const short8*)(src + row * Dd + col);
    }
    __syncthreads();

    short* dst = vt + (long)head * Dd * Tt + t0;
#pragma unroll
    for (int i = 0; i < 4; ++i) {
        int u = tid + i * 256;
        int d = u >> 3, t8 = (u & 7) * 8;
        short8 v;
#pragma unroll
        for (int j = 0; j < 8; ++j)
            v[j] = f2bf(bf2f(tile[(t8 + j) * 136 + d]) * wks[t8 + j]);
        *(short8*)(dst + (long)d * Tt + t8) = v;
    }
}

// ---------------- Kernel 2: barrier-light MFMA attention + fused LN --------
// block = 256 (4 waves), grid = (T/32, B*C). K/Vt B-frags direct from global.
__global__ __launch_bounds__(256, 4)
void k_attn(const short* __restrict__ qb, const short* __restrict__ kbp,
            const short* __restrict__ vtp, const float* __restrict__ x,
            const int* __restrict__ pm,
            const float* __restrict__ lsg, const float* __restrict__ lng,
            const float* __restrict__ lnb, float* __restrict__ out)
{
    const int head = blockIdx.y;
    const int b    = head >> 5;
    const int c    = head & 31;
    const int qt0  = blockIdx.x * 32;
    const int tid  = threadIdx.x;
    const int w    = tid >> 6;
    const int lane = tid & 63;
    const int quad = lane >> 4;
    const int m    = lane & 15;

    __shared__ short S[32 * SROW];       // 33.3 KB
    __shared__ u32   pkbits[16];         // p_mask bitmask, k=0..511
    __shared__ float rlS[32];
    __shared__ float ps1[4][32];
    __shared__ float ps2[4][32];
    __shared__ float mrs[32][2];

    // ---- p_mask bitmask via ballot ----
#pragma unroll
    for (int p = 0; p < 2; ++p) {
        int i = p * 256 + tid;
        bool v = pm[((long)b * Tt + i) * Cc + c] != 0;
        unsigned long long bal = __ballot(v);
        if (lane == 0) {
            pkbits[p * 8 + w * 2]     = (u32)bal;
            pkbits[p * 8 + w * 2 + 1] = (u32)(bal >> 32);
        }
    }

    // Q A-frags (q pre-scaled by SCALE in k_qkvm)
    short8 qf[2][4];
#pragma unroll
    for (int qt = 0; qt < 2; ++qt)
#pragma unroll
        for (int kb = 0; kb < 4; ++kb)
            qf[qt][kb] = *(const short8*)(qb + ((long)head * Tt + qt0 + qt * 16 + m) * Dd
                                          + kb * 32 + quad * 8);
    __syncthreads();

    // ---- QK^T: no barriers, B-frags direct from global (L2-hot) ----
#pragma unroll 2
    for (int ch = 0; ch < 8; ++ch) {
        const short* kp = kbp + ((long)head * Tt + ch * 64 + w * 16 + m) * Dd + quad * 8;
        floatx4 sc0 = {0.f, 0.f, 0.f, 0.f}, sc1 = {0.f, 0.f, 0.f, 0.f};
#pragma unroll
        for (int kb = 0; kb < 4; ++kb) {
            short8 bk = *(const short8*)(kp + kb * 32);
            sc0 = __builtin_amdgcn_mfma_f32_16x16x32_bf16(qf[0][kb], bk, sc0, 0, 0, 0);
            sc1 = __builtin_amdgcn_mfma_f32_16x16x32_bf16(qf[1][kb], bk, sc1, 0, 0, 0);
        }
        int kt = ch * 64 + w * 16 + m;
        u32 wbits = pkbits[ch * 2 + ((w * 16 + m) >> 5)];
        bool masked = (wbits >> ((w * 16 + m) & 31)) & 1;
#pragma unroll
        for (int r = 0; r < 4; ++r) {
            S[(quad * 4 + r) * SROW + kt]      = f2bf(masked ? -1e30f : sc0[r]);
            S[(16 + quad * 4 + r) * SROW + kt] = f2bf(masked ? -1e30f : sc1[r]);
        }
    }
    __syncthreads();

    // ---- softmax: P = exp(s-mx) (wk folded into Vt) ----
    {
        int qi = tid >> 3, part = tid & 7;
        float mx = -1e30f;
        for (int j = 0; j < 64; ++j) mx = fmaxf(mx, bf2f(S[qi * SROW + j * 8 + part]));
        mx = fmaxf(mx, __shfl_xor(mx, 1, 64));
        mx = fmaxf(mx, __shfl_xor(mx, 2, 64));
        mx = fmaxf(mx, __shfl_xor(mx, 4, 64));
        float l = 0.f;
        for (int j = 0; j < 64; ++j) {
            int kt = j * 8 + part;
            float s = bf2f(S[qi * SROW + kt]);
            float e = (s <= -1e29f) ? 0.f : __expf(s - mx);
            S[qi * SROW + kt] = f2bf(e);
            l += e;
        }
        l += __shfl_xor(l, 1, 64);
        l += __shfl_xor(l, 2, 64);
        l += __shfl_xor(l, 4, 64);
        if (part == 0) {
            bool qmask = (pkbits[blockIdx.x] >> qi) & 1;
            rlS[qi] = (l > 0.f && !qmask) ? 1.0f / l : 0.f;
        }
    }
    __syncthreads();

    // ---- PV: A-frags from S-LDS, B-frags direct from Vt global ----
    floatx4 oa[2][2];
#pragma unroll
    for (int qt = 0; qt < 2; ++qt)
#pragma unroll
        for (int dt = 0; dt < 2; ++dt) oa[qt][dt] = (floatx4){0.f, 0.f, 0.f, 0.f};

    const short* vbase = vtp + (long)head * Dd * Tt;
#pragma unroll 2
    for (int ch = 0; ch < 8; ++ch) {
#pragma unroll
        for (int kb = 0; kb < 2; ++kb) {
            int tcol = ch * 64 + kb * 32 + quad * 8;
            short8 bv0 = *(const short8*)(vbase + ((long)((w * 2 + 0) * 16 + m)) * Tt + tcol);
            short8 bv1 = *(const short8*)(vbase + ((long)((w * 2 + 1) * 16 + m)) * Tt + tcol);
#pragma unroll
            for (int qt = 0; qt < 2; ++qt) {
                short8 ap = *(const short8*)&S[(qt * 16 + m) * SROW + tcol];
                oa[qt][0] = __builtin_amdgcn_mfma_f32_16x16x32_bf16(ap, bv0, oa[qt][0], 0, 0, 0);
                oa[qt][1] = __builtin_amdgcn_mfma_f32_16x16x32_bf16(ap, bv1, oa[qt][1], 0, 0, 0);
            }
        }
    }

    // ---- epilogue: y = x + ls*(O*rl); LayerNorm over d=128 ----
    float yv[2][2][4];
    float s1[2][4], s2[2][4];
#pragma unroll
    for (int qt = 0; qt < 2; ++qt)
#pragma unroll
        for (int r = 0; r < 4; ++r) { s1[qt][r] = 0.f; s2[qt][r] = 0.f; }

#pragma unroll
    for (int qt = 0; qt < 2; ++qt)
#pragma unroll
        for (int dt = 0; dt < 2; ++dt) {
            int d = (w * 2 + dt) * 16 + m;
            float lg = lsg[d];
#pragma unroll
            for (int r = 0; r < 4; ++r) {
                int row = qt * 16 + quad * 4 + r;
                int t = qt0 + row;
                float val = oa[qt][dt][r] * rlS[row];
                float y = x[(((long)b * Tt + t) * Cc + c) * Dd + d] + lg * val;
                yv[qt][dt][r] = y;
                s1[qt][r] += y;
                s2[qt][r] += y * y;
            }
        }
#pragma unroll
    for (int qt = 0; qt < 2; ++qt)
#pragma unroll
        for (int r = 0; r < 4; ++r) {
            float a = s1[qt][r], bb = s2[qt][r];
            a += __shfl_xor(a, 1, 64); bb += __shfl_xor(bb, 1, 64);
            a += __shfl_xor(a, 2, 64); bb += __shfl_xor(bb, 2, 64);
            a += __shfl_xor(a, 4, 64); bb += __shfl_xor(bb, 4, 64);
            a += __shfl_xor(a, 8, 64); bb += __shfl_xor(bb, 8, 64);
            if (m == 0) {
                ps1[w][qt * 16 + quad * 4 + r] = a;
                ps2[w][qt * 16 + quad * 4 + r] = bb;
            }
        }
    __syncthreads();
    if (tid < 32) {
        float a = 0.f, bb = 0.f;
#pragma unroll
        for (int wv = 0; wv < 4; ++wv) { a += ps1[wv][tid]; bb += ps2[wv][tid]; }
        float mean = a * (1.0f / Dd);
        float var  = bb * (1.0f / Dd) - mean * mean;
        mrs[tid][0] = mean;
        mrs[tid][1] = rsqrtf(var + 1e-5f);
    }
    __syncthreads();

#pragma unroll
    for (int qt = 0; qt < 2; ++qt)
#pragma unroll
        for (int dt = 0; dt < 2; ++dt) {
            int d = (w * 2 + dt) * 16 + m;
            float g = lng[d], be = lnb[d];
#pragma unroll
            for (int r = 0; r < 4; ++r) {
                int row = qt * 16 + quad * 4 + r;
                int t = qt0 + row;
                out[(((long)b * Tt + t) * Cc + c) * Dd + d] =
                    (yv[qt][dt][r] - mrs[row][0]) * mrs[row][1] * g + be;
            }
        }
}

extern "C" void kernel_launch(void* const* d_in, const int* in_sizes, int n_in,
                              void* d_out, int out_size, void* d_ws, size_t ws_size,
                              hipStream_t stream) {
    const float* x    = (const float*)d_in[0];
    const int* xmask  = (const int*)d_in[1];
    const int* pmask  = (const int*)d_in[2];
    const int* pos    = (const int*)d_in[3];
    const float* pe   = (const float*)d_in[4];
    const int* imp    = (const int*)d_in[5];
    const int* idxc   = (const int*)d_in[6];
    const float* wq_w = (const float*)d_in[7];
    const float* wq_b = (const float*)d_in[8];
    const float* wk_w = (const float*)d_in[9];
    const float* wk_b = (const float*)d_in[10];
    const float* wv_w = (const float*)d_in[11];
    const float* wv_b = (const float*)d_in[12];
    const float* lsg  = (const float*)d_in[13];
    const float* lng  = (const float*)d_in[14];
    const float* lnb  = (const float*)d_in[15];
    float* out = (float*)d_out;

    size_t n = (size_t)Bb * Cc * Tt * Dd;
    short* qb = (short*)d_ws;
    short* kb = qb + n;
    short* vb = kb + n;
    short* vt = vb + n;
    short* Wb = vt + n;

    k_wconv<<<dim3(3 * Dd * Dd / 256), dim3(256), 0, stream>>>(wq_w, wk_w, wv_w, Wb);
    k_qkvm<<<dim3(Bb * Tt * Cc / 64), dim3(256), 0, stream>>>(
        x, xmask, pos, pe, imp, idxc, Wb, wq_b, wk_b, wv_b, qb, kb, vb);
    k_vt<<<dim3(Tt / 64, Bb * Cc), dim3(256), 0, stream>>>(vb, xmask, vt);
    k_attn<<<dim3(Tt / 32, Bb * Cc), dim3(256), 0, stream>>>(
        qb, kb, vt, x, pmask, lsg, lng, lnb, out);
}

// Round 5
// 327.541 us; speedup vs baseline: 5.7711x; 1.0742x over previous
//
#include <hip/hip_runtime.h>
#include <hip/hip_bf16.h>

#define Bb 8
#define Tt 512
#define Cc 32
#define Dd 128
#define SCALE 0.08838834764831845f
#define SROW 520  // S row stride in bf16 elems (512 + 8 pad, 16B-aligned)

typedef unsigned int u32;
typedef __hip_bfloat16 bf16;
typedef __attribute__((ext_vector_type(8))) short short8;
typedef __attribute__((ext_vector_type(4))) short short4v;
typedef __attribute__((ext_vector_type(4))) float floatx4;

__device__ __forceinline__ short f2bf(float f) {
    __hip_bfloat16 h = __float2bfloat16(f);
    return *(short*)&h;
}
__device__ __forceinline__ float bf2f(short s) {
    return __uint_as_float(((u32)(unsigned short)s) << 16);
}

// ---------------- Kernel 0: W f32 -> bf16 ----------------
__global__ __launch_bounds__(256)
void k_wconv(const float* __restrict__ wq, const float* __restrict__ wk,
             const float* __restrict__ wv, short* __restrict__ Wb)
{
    int g = blockIdx.x * 256 + threadIdx.x;
    int mat = g >> 14, rem = g & 16383;
    const float* src = (mat == 0) ? wq : (mat == 1) ? wk : wv;
    Wb[g] = f2bf(src[rem]);
}

// ---------------- Kernel 1: gather + QKV (MFMA) + rotation + q*SCALE -------
__global__ __launch_bounds__(256)
void k_qkvm(const float* __restrict__ x, const int* __restrict__ xm,
            const int* __restrict__ pos, const float* __restrict__ pe,
            const int* __restrict__ imp, const int* __restrict__ idxc,
            const short* __restrict__ Wb,
            const float* __restrict__ bq, const float* __restrict__ bk,
            const float* __restrict__ bv,
            short* __restrict__ qb, short* __restrict__ kb, short* __restrict__ vb)
{
    const int R0  = blockIdx.x * 64;
    const int b   = R0 >> 14;
    const int t0  = (R0 >> 5) & 511;
    const int tid = threadIdx.x;
    const int w    = tid >> 6;
    const int lane = tid & 63;
    const int quad = lane >> 4;
    const int m    = lane & 15;

    __shared__ short xg[64 * 136];
    __shared__ short ot[64 * 392];

#pragma unroll
    for (int i = 0; i < 8; ++i) {
        int u   = tid + i * 256;
        int row = u >> 5, seg = u & 31;
        int R   = R0 + row;
        int idx = xm[R] ? imp[R >> 5] : idxc[R];
        float4 v = *(const float4*)(x + ((long)(R >> 5) * Cc + idx) * Dd + seg * 4);
        short4v s = {f2bf(v.x), f2bf(v.y), f2bf(v.z), f2bf(v.w)};
        *(short4v*)&xg[row * 136 + seg * 4] = s;
    }

    short8 wf[6][4];
    float  bias_v[6];
#pragma unroll
    for (int mat = 0; mat < 3; ++mat) {
        const float* bp = (mat == 0) ? bq : (mat == 1) ? bk : bv;
#pragma unroll
        for (int h = 0; h < 2; ++h) {
            int sl = mat * 2 + h;
            int ct = h * 4 + w;
            bias_v[sl] = bp[ct * 16 + m];
#pragma unroll
            for (int kb = 0; kb < 4; ++kb)
                wf[sl][kb] = *(const short8*)(Wb + ((long)mat * 128 + ct * 16 + m) * 128
                                              + kb * 32 + quad * 8);
        }
    }
    __syncthreads();

    for (int rt = 0; rt < 4; ++rt) {
        short8 af[4];
#pragma unroll
        for (int kb = 0; kb < 4; ++kb)
            af[kb] = *(const short8*)&xg[(rt * 16 + m) * 136 + kb * 32 + quad * 8];

        floatx4 acc[6];
#pragma unroll
        for (int sl = 0; sl < 6; ++sl) acc[sl] = (floatx4){0.f, 0.f, 0.f, 0.f};
#pragma unroll
        for (int kb = 0; kb < 4; ++kb)
#pragma unroll
            for (int sl = 0; sl < 6; ++sl)
                acc[sl] = __builtin_amdgcn_mfma_f32_16x16x32_bf16(af[kb], wf[sl][kb], acc[sl], 0, 0, 0);

        int po[4];
#pragma unroll
        for (int r = 0; r < 4; ++r) po[r] = pos[R0 + rt * 16 + quad * 4 + r];

#pragma unroll
        for (int sl = 0; sl < 6; ++sl) {
            int mat = sl >> 1;
            int ct  = (sl & 1) * 4 + w;
            int d   = ct * 16 + m;
#pragma unroll
            for (int r = 0; r < 4; ++r) {
                float v = acc[sl][r] + bias_v[sl];
                float p = __shfl_xor(v, 1, 64);
                if (mat < 2) {
                    const float* rp = pe + ((long)po[r] * (Dd / 2) + (d >> 1)) * 2;
                    float r0 = rp[0], r1 = rp[1];
                    v = (d & 1) ? fmaf(p, r1, v * r0) : fmaf(v, r0, -(p * r1));
                    if (mat == 0) v *= SCALE;
                }
                ot[(rt * 16 + quad * 4 + r) * 392 + mat * 128 + d] = f2bf(v);
            }
        }
    }
    __syncthreads();

    short* const mats[3] = {qb, kb, vb};
#pragma unroll
    for (int mat = 0; mat < 3; ++mat) {
        short* dst = mats[mat];
#pragma unroll
        for (int i = 0; i < 4; ++i) {
            int g = tid + i * 256;
            int n = g >> 4, off = (g & 15) * 8;
            int c = n & 31, tl = n >> 5;
            *(short8*)(dst + (((long)(b * Cc + c) * Tt) + t0 + tl) * Dd + off) =
                *(const short8*)&ot[n * 392 + mat * 128 + off];
        }
    }
}

// ---------------- Kernel 1b: V transpose + wk fold ----------------
__global__ __launch_bounds__(256)
void k_vt(const short* __restrict__ vb, const int* __restrict__ xm,
          short* __restrict__ vt)
{
    const int head = blockIdx.y;
    const int b    = head >> 5;
    const int c    = head & 31;
    const int t0   = blockIdx.x * 64;
    const int tid  = threadIdx.x;

    __shared__ short tile[64 * 136];
    __shared__ float wks[64];

    if (tid < 64)
        wks[tid] = xm[((long)b * Tt + t0 + tid) * Cc + c] ? (1.0f / Tt) : 1.0f;

    const short* src = vb + ((long)head * Tt + t0) * Dd;
#pragma unroll
    for (int i = 0; i < 4; ++i) {
        int u = tid + i * 256;
        int row = u >> 4, col = (u & 15) * 8;
        *(short8*)&tile[row * 136 + col] = *(const short8*)(src + row * Dd + col);
    }
    __syncthreads();

    short* dst = vt + (long)head * Dd * Tt + t0;
#pragma unroll
    for (int i = 0; i < 4; ++i) {
        int u = tid + i * 256;
        int d = u >> 3, t8 = (u & 7) * 8;
        short8 v;
#pragma unroll
        for (int j = 0; j < 8; ++j)
            v[j] = f2bf(bf2f(tile[(t8 + j) * 136 + d]) * wks[t8 + j]);
        *(short8*)(dst + (long)d * Tt + t8) = v;
    }
}

// ---------------- Kernel 2: TQ=64, 8-wave MFMA attention + fused LN --------
// grid = (B*C, T/64)  -> linear id = tile*256 + head => head%8 pins XCD.
__global__ __launch_bounds__(512, 4)
void k_attn(const short* __restrict__ qb, const short* __restrict__ kbp,
            const short* __restrict__ vtp, const float* __restrict__ x,
            const int* __restrict__ pm,
            const float* __restrict__ lsg, const float* __restrict__ lng,
            const float* __restrict__ lnb, float* __restrict__ out)
{
    const int head = blockIdx.x;          // b*C + c
    const int b    = head >> 5;
    const int c    = head & 31;
    const int qt0  = blockIdx.y * 64;
    const int tid  = threadIdx.x;
    const int w    = tid >> 6;            // 0..7
    const int lane = tid & 63;
    const int quad = lane >> 4;
    const int m    = lane & 15;

    __shared__ short S[64 * SROW];        // 66.6 KB
    __shared__ u32   pkbits[16];
    __shared__ float rlS[64];
    __shared__ float ps1[8][64];
    __shared__ float ps2[8][64];
    __shared__ float mrs[64][2];

    // ---- p_mask bits for all 512 tokens of this head ----
    {
        bool v = pm[((long)b * Tt + tid) * Cc + c] != 0;
        unsigned long long bal = __ballot(v);
        if (lane == 0) {
            pkbits[w * 2]     = (u32)bal;
            pkbits[w * 2 + 1] = (u32)(bal >> 32);
        }
    }

    // ---- Q A-frags: 4 q-tiles (q pre-scaled by SCALE) ----
    short8 qf[4][4];
#pragma unroll
    for (int qt = 0; qt < 4; ++qt)
#pragma unroll
        for (int kb = 0; kb < 4; ++kb)
            qf[qt][kb] = *(const short8*)(qb + ((long)head * Tt + qt0 + qt * 16 + m) * Dd
                                          + kb * 32 + quad * 8);
    __syncthreads();

    // ---- QK^T: each wave owns k-strip w*16 within 128-chunks ----
    for (int ch = 0; ch < 4; ++ch) {
        int kt = ch * 128 + w * 16 + m;
        const short* kp = kbp + ((long)head * Tt + kt) * Dd + quad * 8;
        floatx4 sc[4];
#pragma unroll
        for (int qt = 0; qt < 4; ++qt) sc[qt] = (floatx4){0.f, 0.f, 0.f, 0.f};
#pragma unroll
        for (int kb = 0; kb < 4; ++kb) {
            short8 bk = *(const short8*)(kp + kb * 32);
#pragma unroll
            for (int qt = 0; qt < 4; ++qt)
                sc[qt] = __builtin_amdgcn_mfma_f32_16x16x32_bf16(qf[qt][kb], bk, sc[qt], 0, 0, 0);
        }
        bool masked = (pkbits[kt >> 5] >> (kt & 31)) & 1;
#pragma unroll
        for (int qt = 0; qt < 4; ++qt)
#pragma unroll
            for (int r = 0; r < 4; ++r)
                S[(qt * 16 + quad * 4 + r) * SROW + kt] = f2bf(masked ? -1e30f : sc[qt][r]);
    }
    __syncthreads();

    // ---- softmax: row qi = tid>>3, cols part*64..+63, vectorized ----
    {
        int qi = tid >> 3, part = tid & 7;
        short* rowp = &S[qi * SROW + part * 64];
        short8 sv[8];
#pragma unroll
        for (int j = 0; j < 8; ++j) sv[j] = *(short8*)&rowp[j * 8];
        float mx = -1e30f;
#pragma unroll
        for (int j = 0; j < 8; ++j)
#pragma unroll
            for (int e = 0; e < 8; ++e) mx = fmaxf(mx, bf2f(sv[j][e]));
        mx = fmaxf(mx, __shfl_xor(mx, 1, 64));
        mx = fmaxf(mx, __shfl_xor(mx, 2, 64));
        mx = fmaxf(mx, __shfl_xor(mx, 4, 64));
        float l = 0.f;
#pragma unroll
        for (int j = 0; j < 8; ++j)
#pragma unroll
            for (int e = 0; e < 8; ++e) {
                float s = bf2f(sv[j][e]);
                float ex = (s <= -1e29f) ? 0.f : __expf(s - mx);
                sv[j][e] = f2bf(ex);
                l += ex;
            }
#pragma unroll
        for (int j = 0; j < 8; ++j) *(short8*)&rowp[j * 8] = sv[j];
        l += __shfl_xor(l, 1, 64);
        l += __shfl_xor(l, 2, 64);
        l += __shfl_xor(l, 4, 64);
        if (part == 0) {
            int t = qt0 + qi;
            bool qmask = (pkbits[t >> 5] >> (t & 31)) & 1;
            rlS[qi] = (l > 0.f && !qmask) ? 1.0f / l : 0.f;
        }
    }
    __syncthreads();

    // ---- PV: wave owns d-strip w*16..+15; B-frags from Vt global ----
    floatx4 oa[4];
#pragma unroll
    for (int qt = 0; qt < 4; ++qt) oa[qt] = (floatx4){0.f, 0.f, 0.f, 0.f};

    const short* vbase = vtp + (long)head * Dd * Tt + ((long)(w * 16 + m)) * Tt + quad * 8;
    for (int kv = 0; kv < 16; ++kv) {
        short8 bv = *(const short8*)(vbase + kv * 32);
#pragma unroll
        for (int qt = 0; qt < 4; ++qt) {
            short8 ap = *(const short8*)&S[(qt * 16 + m) * SROW + kv * 32 + quad * 8];
            oa[qt] = __builtin_amdgcn_mfma_f32_16x16x32_bf16(ap, bv, oa[qt], 0, 0, 0);
        }
    }

    // ---- epilogue: y = x + ls*(O*rl); LN over d=128 (8-wave partials) ----
    const int d = w * 16 + m;
    const float lg = lsg[d];
    float yv[4][4];
    float s1[4][4], s2[4][4];
#pragma unroll
    for (int qt = 0; qt < 4; ++qt)
#pragma unroll
        for (int r = 0; r < 4; ++r) {
            int row = qt * 16 + quad * 4 + r;
            int t = qt0 + row;
            float val = oa[qt][r] * rlS[row];
            float y = x[(((long)b * Tt + t) * Cc + c) * Dd + d] + lg * val;
            yv[qt][r] = y;
            s1[qt][r] = y;
            s2[qt][r] = y * y;
        }
#pragma unroll
    for (int qt = 0; qt < 4; ++qt)
#pragma unroll
        for (int r = 0; r < 4; ++r) {
            float a = s1[qt][r], bb = s2[qt][r];
            a += __shfl_xor(a, 1, 64); bb += __shfl_xor(bb, 1, 64);
            a += __shfl_xor(a, 2, 64); bb += __shfl_xor(bb, 2, 64);
            a += __shfl_xor(a, 4, 64); bb += __shfl_xor(bb, 4, 64);
            a += __shfl_xor(a, 8, 64); bb += __shfl_xor(bb, 8, 64);
            if (m == 0) {
                ps1[w][qt * 16 + quad * 4 + r] = a;
                ps2[w][qt * 16 + quad * 4 + r] = bb;
            }
        }
    __syncthreads();
    if (tid < 64) {
        float a = 0.f, bb = 0.f;
#pragma unroll
        for (int wv = 0; wv < 8; ++wv) { a += ps1[wv][tid]; bb += ps2[wv][tid]; }
        float mean = a * (1.0f / Dd);
        float var  = bb * (1.0f / Dd) - mean * mean;
        mrs[tid][0] = mean;
        mrs[tid][1] = rsqrtf(var + 1e-5f);
    }
    __syncthreads();

    const float g = lng[d], be = lnb[d];
#pragma unroll
    for (int qt = 0; qt < 4; ++qt)
#pragma unroll
        for (int r = 0; r < 4; ++r) {
            int row = qt * 16 + quad * 4 + r;
            int t = qt0 + row;
            out[(((long)b * Tt + t) * Cc + c) * Dd + d] =
                (yv[qt][r] - mrs[row][0]) * mrs[row][1] * g + be;
        }
}

extern "C" void kernel_launch(void* const* d_in, const int* in_sizes, int n_in,
                              void* d_out, int out_size, void* d_ws, size_t ws_size,
                              hipStream_t stream) {
    const float* x    = (const float*)d_in[0];
    const int* xmask  = (const int*)d_in[1];
    const int* pmask  = (const int*)d_in[2];
    const int* pos    = (const int*)d_in[3];
    const float* pe   = (const float*)d_in[4];
    const int* imp    = (const int*)d_in[5];
    const int* idxc   = (const int*)d_in[6];
    const float* wq_w = (const float*)d_in[7];
    const float* wq_b = (const float*)d_in[8];
    const float* wk_w = (const float*)d_in[9];
    const float* wk_b = (const float*)d_in[10];
    const float* wv_w = (const float*)d_in[11];
    const float* wv_b = (const float*)d_in[12];
    const float* lsg  = (const float*)d_in[13];
    const float* lng  = (const float*)d_in[14];
    const float* lnb  = (const float*)d_in[15];
    float* out = (float*)d_out;

    size_t n = (size_t)Bb * Cc * Tt * Dd;
    short* qb = (short*)d_ws;
    short* kb = qb + n;
    short* vb = kb + n;
    short* vt = vb + n;
    short* Wb = vt + n;

    k_wconv<<<dim3(3 * Dd * Dd / 256), dim3(256), 0, stream>>>(wq_w, wk_w, wv_w, Wb);
    k_qkvm<<<dim3(Bb * Tt * Cc / 64), dim3(256), 0, stream>>>(
        x, xmask, pos, pe, imp, idxc, Wb, wq_b, wk_b, wv_b, qb, kb, vb);
    k_vt<<<dim3(Tt / 64, Bb * Cc), dim3(256), 0, stream>>>(vb, xmask, vt);
    k_attn<<<dim3(Bb * Cc, Tt / 64), dim3(512), 0, stream>>>(
        qb, kb, vt, x, pmask, lsg, lng, lnb, out);
}